// Round 5
// baseline (529.720 us; speedup 1.0000x reference)
//
#include <hip/hip_runtime.h>
#include <math.h>

#define N_NODES 50000
#define N_EDGES 800000
#define IN_DIM 128
#define ED_DIM 32
#define NH 4
#define CH 16
#define HC 64
#define NG 64
#define NCL 2
#define NEG_SLOPE 0.2f
#define LN_EPS 1e-5f
#define NBLK1 196  // ceil(50000/256)

// ---------- fold We @ ae -> Ve[32][8]  (k = layer*4 + head) ----------
__global__ void k_ve(const float* __restrict__ We1, const float* __restrict__ ae1,
                     const float* __restrict__ We2, const float* __restrict__ ae2,
                     float* __restrict__ Ve) {
    int t = threadIdx.x;            // 256 threads
    int d = t >> 3, k = t & 7;
    int l = k >> 2, h = k & 3;
    const float* We = l ? We2 : We1;
    const float* ae = l ? ae2 : ae1;
    float s = 0.f;
    #pragma unroll
    for (int c = 0; c < CH; ++c) s += We[d * HC + h * CH + c] * ae[h * CH + c];
    Ve[d * 8 + k] = s;
}

// ---------- degree histogram ----------
__global__ void k_hist(const int* __restrict__ dst, int* __restrict__ cnt) {
    int e = blockIdx.x * 256 + threadIdx.x;
    if (e < N_EDGES) atomicAdd(&cnt[dst[e]], 1);
}

// ---------- 3-phase exclusive scan of cnt -> row_start (+ rp copy) ----------
__global__ void k_scan_local(const int* __restrict__ cnt, int* __restrict__ tmp_ex,
                             int* __restrict__ bsum) {
    __shared__ int sd[256];
    int t = threadIdx.x, idx = blockIdx.x * 256 + t;
    int v = (idx < N_NODES) ? cnt[idx] : 0;
    sd[t] = v; __syncthreads();
    for (int off = 1; off < 256; off <<= 1) {
        int add = (t >= off) ? sd[t - off] : 0;
        __syncthreads();
        sd[t] += add;
        __syncthreads();
    }
    if (idx < N_NODES) tmp_ex[idx] = sd[t] - v;
    if (t == 255) bsum[blockIdx.x] = sd[t];
}

__global__ void k_scan_bsums(const int* __restrict__ bsum, int* __restrict__ boff) {
    __shared__ int sd[256];
    int t = threadIdx.x;
    int v = (t < NBLK1) ? bsum[t] : 0;
    sd[t] = v; __syncthreads();
    for (int off = 1; off < 256; off <<= 1) {
        int add = (t >= off) ? sd[t - off] : 0;
        __syncthreads();
        sd[t] += add;
        __syncthreads();
    }
    boff[t] = sd[t] - v;
}

__global__ void k_scan_final(const int* __restrict__ tmp_ex, const int* __restrict__ boff,
                             int* __restrict__ row_start, int* __restrict__ rp) {
    int idx = blockIdx.x * 256 + threadIdx.x;
    if (idx < N_NODES) {
        int v = tmp_ex[idx] + boff[blockIdx.x];
        row_start[idx] = v;
        rp[idx] = v;
    }
    if (idx == 0) row_start[N_NODES] = N_EDGES;
}

// ---------- pure streaming: ale_edge[e][8] for both layers ----------
__global__ void k_edge(const float* __restrict__ ea, const float* __restrict__ Ve,
                       float* __restrict__ ale_edge) {
    __shared__ float sVe[ED_DIM * 8];
    int t = threadIdx.x;
    if (t < ED_DIM * 8) sVe[t] = Ve[t];
    __syncthreads();
    int e = blockIdx.x * 256 + t;
    if (e >= N_EDGES) return;
    float a[8];
    #pragma unroll
    for (int k = 0; k < 8; ++k) a[k] = 0.f;
    const float4* er4 = (const float4*)(ea + (long long)e * ED_DIM);
    #pragma unroll
    for (int q = 0; q < ED_DIM / 4; ++q) {
        float4 v = er4[q];
        float ev[4] = {v.x, v.y, v.z, v.w};
        #pragma unroll
        for (int u = 0; u < 4; ++u) {
            #pragma unroll
            for (int k = 0; k < 8; ++k) a[k] += ev[u] * sVe[(q * 4 + u) * 8 + k];
        }
    }
    float4* ap = (float4*)(ale_edge + (long long)e * 8);
    ap[0] = make_float4(a[0], a[1], a[2], a[3]);
    ap[1] = make_float4(a[4], a[5], a[6], a[7]);
}

// ---------- scatter only the 4B edge id into CSR slots ----------
__global__ void k_perm(const int* __restrict__ dst, int* __restrict__ rp,
                       int* __restrict__ perm_csr) {
    int e = blockIdx.x * 256 + threadIdx.x;
    if (e >= N_EDGES) return;
    int d = dst[e];
    int pos = atomicAdd(&rp[d], 1);
    perm_csr[pos] = e;
}

// ---------- xw = X @ W  (+ fused per-head al_src / al_dst), 8 nodes/block ----------
template<int K>
__global__ void k_xw(const float* __restrict__ X, const float* __restrict__ W,
                     const float* __restrict__ AS, const float* __restrict__ AD,
                     float* __restrict__ XW, float* __restrict__ ALS, float* __restrict__ ALD) {
    __shared__ float sW[K * HC];
    __shared__ float sX[8 * K];
    int t = threadIdx.x;
    for (int i = t; i < K * HC; i += 256) sW[i] = W[i];
    int nb = blockIdx.x * 8;
    for (int i = t; i < 8 * K; i += 256) sX[i] = X[(long long)nb * K + i];
    __syncthreads();
    int sub = t >> 6, j = t & 63;
    const float* x0 = &sX[sub * K];
    const float* x1 = &sX[(sub + 4) * K];
    float acc0 = 0.f, acc1 = 0.f;
    #pragma unroll 8
    for (int k = 0; k < K; ++k) {
        float wv = sW[k * HC + j];
        acc0 += x0[k] * wv;
        acc1 += x1[k] * wv;
    }
    int n0 = nb + sub, n1 = nb + sub + 4;
    XW[(long long)n0 * HC + j] = acc0;
    XW[(long long)n1 * HC + j] = acc1;
    float as_ = AS[j], ad_ = AD[j];
    float vs0 = acc0 * as_, vd0 = acc0 * ad_;
    float vs1 = acc1 * as_, vd1 = acc1 * ad_;
    #pragma unroll
    for (int m = 1; m < 16; m <<= 1) {
        vs0 += __shfl_xor(vs0, m); vd0 += __shfl_xor(vd0, m);
        vs1 += __shfl_xor(vs1, m); vd1 += __shfl_xor(vd1, m);
    }
    if ((j & 15) == 0) {
        int h = j >> 4;
        ALS[n0 * 4 + h] = vs0; ALD[n0 * 4 + h] = vd0;
        ALS[n1 * 4 + h] = vs1; ALD[n1 * 4 + h] = vd1;
    }
}

// ---------- wave-per-node softmax aggregation (+self-loop, bias/ReLU[/LN]) ----------
// Plain exp (no max shift): alphas are bounded (|a| <~ 10) by construction.
template<bool DO_LN>
__global__ void k_agg(const int* __restrict__ rs, const int* __restrict__ perm,
                      const int* __restrict__ srcI,
                      const float* __restrict__ ale, int ale_off,
                      const float* __restrict__ ALS, const float* __restrict__ ALD,
                      const float* __restrict__ XW, const float* __restrict__ bias,
                      const float* __restrict__ gam, const float* __restrict__ bet,
                      float* __restrict__ OUT) {
    int n = (blockIdx.x * blockDim.x + threadIdx.x) >> 6;
    if (n >= N_NODES) return;
    int lane = threadIdx.x & 63;
    int h = lane >> 4;
    int e0 = rs[n], e1 = rs[n + 1];
    float adn = ALD[n * 4 + h];
    float acc0 = 0.f, l0 = 0.f, as0 = 0.f;
    float acc1 = 0.f, l1 = 0.f, as1 = 0.f;
    float acc2 = 0.f, l2 = 0.f, as2 = 0.f;
    float acc3 = 0.f, l3 = 0.f, as3 = 0.f;
    int e = e0;
    for (; e + 3 < e1; e += 4) {
        int eA = perm[e], eB = perm[e + 1], eC = perm[e + 2], eD = perm[e + 3];
        int sA = srcI[eA], sB = srcI[eB], sC = srcI[eC], sD = srcI[eD];
        float aeA = ale[(long long)eA * 8 + ale_off + h];
        float aeB = ale[(long long)eB * 8 + ale_off + h];
        float aeC = ale[(long long)eC * 8 + ale_off + h];
        float aeD = ale[(long long)eD * 8 + ale_off + h];
        float xA = XW[sA * HC + lane];
        float xB = XW[sB * HC + lane];
        float xC = XW[sC * HC + lane];
        float xD = XW[sD * HC + lane];
        float aA = ALS[sA * 4 + h] + adn + aeA;
        float aB = ALS[sB * 4 + h] + adn + aeB;
        float aC = ALS[sC * 4 + h] + adn + aeC;
        float aD = ALS[sD * 4 + h] + adn + aeD;
        aA = aA > 0.f ? aA : NEG_SLOPE * aA;
        aB = aB > 0.f ? aB : NEG_SLOPE * aB;
        aC = aC > 0.f ? aC : NEG_SLOPE * aC;
        aD = aD > 0.f ? aD : NEG_SLOPE * aD;
        float qA = __expf(aA), qB = __expf(aB), qC = __expf(aC), qD = __expf(aD);
        acc0 += qA * xA; l0 += qA; as0 += aeA;
        acc1 += qB * xB; l1 += qB; as1 += aeB;
        acc2 += qC * xC; l2 += qC; as2 += aeC;
        acc3 += qD * xD; l3 += qD; as3 += aeD;
    }
    for (; e < e1; ++e) {
        int eA = perm[e];
        int sA = srcI[eA];
        float aeA = ale[(long long)eA * 8 + ale_off + h];
        float xA = XW[sA * HC + lane];
        float aA = ALS[sA * 4 + h] + adn + aeA;
        aA = aA > 0.f ? aA : NEG_SLOPE * aA;
        float qA = __expf(aA);
        acc0 += qA * xA; l0 += qA; as0 += aeA;
    }
    // self loop: ale_self = mean of row's ale (linearity of edge projection)
    int d = e1 - e0;
    float invd = 1.f / (float)(d > 0 ? d : 1);
    float aSelf = ALS[n * 4 + h] + adn + (as0 + as1 + as2 + as3) * invd;
    aSelf = aSelf > 0.f ? aSelf : NEG_SLOPE * aSelf;
    float pS = __expf(aSelf);
    float acc = (acc0 + acc1) + (acc2 + acc3) + pS * XW[n * HC + lane];
    float l = (l0 + l1) + (l2 + l3) + pS;
    float v = acc / (l + 1e-16f) + bias[lane];
    v = fmaxf(v, 0.f);
    if (DO_LN) {
        float s1 = v;
        #pragma unroll
        for (int mm = 1; mm < 64; mm <<= 1) s1 += __shfl_xor(s1, mm);
        float mean = s1 * (1.f / 64.f);
        float dd = v - mean;
        float s2 = dd * dd;
        #pragma unroll
        for (int mm = 1; mm < 64; mm <<= 1) s2 += __shfl_xor(s2, mm);
        float var = s2 * (1.f / 64.f);
        v = dd * rsqrtf(var + LN_EPS) * gam[lane] + bet[lane];
    }
    OUT[(long long)n * HC + lane] = v;
}

// ---------- global max pool by (sorted) batch; values >= 0 ----------
__global__ void k_pool(const float* __restrict__ H2, const int* __restrict__ batch,
                       float* __restrict__ pooled) {
    int j = threadIdx.x & 63;
    int r = threadIdx.x >> 6;          // 4 rows in parallel
    int base = blockIdx.x * 128;
    int gcur = -1; float rm = 0.f;
    for (int n = base + r; n < base + 128 && n < N_NODES; n += 4) {
        int g = batch[n];
        if (g != gcur) {
            if (gcur >= 0) atomicMax((unsigned int*)&pooled[gcur * HC + j], __float_as_uint(rm));
            gcur = g; rm = 0.f;
        }
        rm = fmaxf(rm, H2[(long long)n * HC + j]);
    }
    if (gcur >= 0) atomicMax((unsigned int*)&pooled[gcur * HC + j], __float_as_uint(rm));
}

// ---------- head: fc1 + LN + relu + fc2 + log_softmax ----------
__global__ void k_head(const float* __restrict__ pooled,
                       const float* __restrict__ fw1, const float* __restrict__ fb1,
                       const float* __restrict__ g2, const float* __restrict__ be2,
                       const float* __restrict__ fw2, const float* __restrict__ fb2,
                       float* __restrict__ out) {
    int g = blockIdx.x;
    int j = threadIdx.x;                // 64 threads, lanes 0..31 active for math
    float z = 0.f;
    if (j < 32) {
        for (int k = 0; k < HC; ++k) z += pooled[g * HC + k] * fw1[k * 32 + j];
        z += fb1[j];
    }
    float s1 = (j < 32) ? z : 0.f;
    for (int m = 1; m < 32; m <<= 1) s1 += __shfl_xor(s1, m, 32);
    float mean = s1 * (1.f / 32.f);
    float d = z - mean;
    float s2 = (j < 32) ? d * d : 0.f;
    for (int m = 1; m < 32; m <<= 1) s2 += __shfl_xor(s2, m, 32);
    float var = s2 * (1.f / 32.f);
    float zz = 0.f;
    if (j < 32) {
        zz = d * rsqrtf(var + LN_EPS) * g2[j] + be2[j];
        zz = fmaxf(zz, 0.f);
    }
    float p0 = (j < 32) ? zz * fw2[j * NCL + 0] : 0.f;
    float p1 = (j < 32) ? zz * fw2[j * NCL + 1] : 0.f;
    for (int m = 1; m < 32; m <<= 1) { p0 += __shfl_xor(p0, m, 32); p1 += __shfl_xor(p1, m, 32); }
    if (j == 0) {
        float l0 = p0 + fb2[0], l1 = p1 + fb2[1];
        float mx = fmaxf(l0, l1);
        float ls = mx + logf(__expf(l0 - mx) + __expf(l1 - mx));
        out[g * NCL + 0] = l0 - ls;
        out[g * NCL + 1] = l1 - ls;
    }
}

extern "C" void kernel_launch(void* const* d_in, const int* in_sizes, int n_in,
                              void* d_out, int out_size, void* d_ws, size_t ws_size,
                              hipStream_t stream) {
    const float* x   = (const float*)d_in[0];
    const float* ea  = (const float*)d_in[1];
    const float* W1  = (const float*)d_in[2];
    const float* as1 = (const float*)d_in[3];
    const float* ad1 = (const float*)d_in[4];
    const float* We1 = (const float*)d_in[5];
    const float* ae1 = (const float*)d_in[6];
    const float* b1  = (const float*)d_in[7];
    const float* W2  = (const float*)d_in[8];
    const float* as2 = (const float*)d_in[9];
    const float* ad2 = (const float*)d_in[10];
    const float* We2 = (const float*)d_in[11];
    const float* ae2 = (const float*)d_in[12];
    const float* b2  = (const float*)d_in[13];
    const float* g1  = (const float*)d_in[14];
    const float* be1 = (const float*)d_in[15];
    const float* fw1 = (const float*)d_in[16];
    const float* fb1 = (const float*)d_in[17];
    const float* g2  = (const float*)d_in[18];
    const float* be2 = (const float*)d_in[19];
    const float* fw2 = (const float*)d_in[20];
    const float* fb2 = (const float*)d_in[21];
    const int* eidx  = (const int*)d_in[22];
    const int* batch = (const int*)d_in[23];
    const int* srcI = eidx;
    const int* dstI = eidx + N_EDGES;

    char* w = (char*)d_ws;
    auto alloc = [&](size_t bytes) { char* p = w; w += (bytes + 255) & ~(size_t)255; return p; };
    int*   cnt       = (int*)  alloc((size_t)N_NODES * 4);
    int*   row_start = (int*)  alloc((size_t)(N_NODES + 1) * 4);
    int*   rp        = (int*)  alloc((size_t)N_NODES * 4);
    int*   tmp_ex    = (int*)  alloc((size_t)N_NODES * 4);
    int*   bsum      = (int*)  alloc(256 * 4);
    int*   boff      = (int*)  alloc(256 * 4);
    float* Ve        = (float*)alloc(ED_DIM * 8 * 4);
    int*   perm_csr  = (int*)  alloc((size_t)N_EDGES * 4);
    float* ale_edge  = (float*)alloc((size_t)N_EDGES * 8 * 4);
    float* xw1       = (float*)alloc((size_t)N_NODES * HC * 4);   // reused as xw2
    float* als1      = (float*)alloc((size_t)N_NODES * 4 * 4);
    float* ald1      = (float*)alloc((size_t)N_NODES * 4 * 4);
    float* h1        = (float*)alloc((size_t)N_NODES * HC * 4);   // reused as h2
    float* als2      = (float*)alloc((size_t)N_NODES * 4 * 4);
    float* ald2      = (float*)alloc((size_t)N_NODES * 4 * 4);
    float* pooled    = (float*)alloc((size_t)NG * HC * 4);
    float* xw2 = xw1;   // lifetime of xw1 ends at k_agg<true>
    float* h2  = h1;    // lifetime of h1 ends at k_xw<HC>

    hipMemsetAsync(cnt, 0, (size_t)N_NODES * 4, stream);
    hipMemsetAsync(pooled, 0, (size_t)NG * HC * 4, stream);

    k_ve<<<1, 256, 0, stream>>>(We1, ae1, We2, ae2, Ve);
    k_hist<<<N_EDGES / 256, 256, 0, stream>>>(dstI, cnt);
    k_scan_local<<<NBLK1, 256, 0, stream>>>(cnt, tmp_ex, bsum);
    k_scan_bsums<<<1, 256, 0, stream>>>(bsum, boff);
    k_scan_final<<<NBLK1, 256, 0, stream>>>(tmp_ex, boff, row_start, rp);
    k_edge<<<N_EDGES / 256, 256, 0, stream>>>(ea, Ve, ale_edge);
    k_perm<<<N_EDGES / 256, 256, 0, stream>>>(dstI, rp, perm_csr);

    // Layer 1: xw + attention logits, aggregate with fused bias/ReLU/LayerNorm
    k_xw<IN_DIM><<<N_NODES / 8, 256, 0, stream>>>(x, W1, as1, ad1, xw1, als1, ald1);
    k_agg<true><<<N_NODES / 4, 256, 0, stream>>>(row_start, perm_csr, srcI, ale_edge, 0,
                                                 als1, ald1, xw1, b1, g1, be1, h1);
    // Layer 2: fused bias/ReLU only
    k_xw<HC><<<N_NODES / 8, 256, 0, stream>>>(h1, W2, as2, ad2, xw2, als2, ald2);
    k_agg<false><<<N_NODES / 4, 256, 0, stream>>>(row_start, perm_csr, srcI, ale_edge, 4,
                                                  als2, ald2, xw2, b2, nullptr, nullptr, h2);

    k_pool<<<(N_NODES + 127) / 128, 256, 0, stream>>>(h2, batch, pooled);
    k_head<<<NG, 64, 0, stream>>>(pooled, fw1, fb1, g2, be2, fw2, fb2, (float*)d_out);
}

// Round 6
// 500.444 us; speedup vs baseline: 1.0585x; 1.0585x over previous
//
#include <hip/hip_runtime.h>
#include <math.h>

#define N_NODES 50000
#define N_EDGES 800000
#define IN_DIM 128
#define ED_DIM 32
#define NH 4
#define CH 16
#define HC 64
#define NG 64
#define NCL 2
#define NEG_SLOPE 0.2f
#define LN_EPS 1e-5f
#define NBLK1 196  // ceil(50000/256)

// ---------- fold We @ ae -> Ve[32][8]  (k = layer*4 + head) ----------
__global__ void k_ve(const float* __restrict__ We1, const float* __restrict__ ae1,
                     const float* __restrict__ We2, const float* __restrict__ ae2,
                     float* __restrict__ Ve) {
    int t = threadIdx.x;            // 256 threads
    int d = t >> 3, k = t & 7;
    int l = k >> 2, h = k & 3;
    const float* We = l ? We2 : We1;
    const float* ae = l ? ae2 : ae1;
    float s = 0.f;
    #pragma unroll
    for (int c = 0; c < CH; ++c) s += We[d * HC + h * CH + c] * ae[h * CH + c];
    Ve[d * 8 + k] = s;
}

// ---------- degree histogram ----------
__global__ void k_hist(const int* __restrict__ dst, int* __restrict__ cnt) {
    int e = blockIdx.x * 256 + threadIdx.x;
    if (e < N_EDGES) atomicAdd(&cnt[dst[e]], 1);
}

// ---------- 3-phase exclusive scan of cnt -> row_start (+ rp copy) ----------
__global__ void k_scan_local(const int* __restrict__ cnt, int* __restrict__ tmp_ex,
                             int* __restrict__ bsum) {
    __shared__ int sd[256];
    int t = threadIdx.x, idx = blockIdx.x * 256 + t;
    int v = (idx < N_NODES) ? cnt[idx] : 0;
    sd[t] = v; __syncthreads();
    for (int off = 1; off < 256; off <<= 1) {
        int add = (t >= off) ? sd[t - off] : 0;
        __syncthreads();
        sd[t] += add;
        __syncthreads();
    }
    if (idx < N_NODES) tmp_ex[idx] = sd[t] - v;
    if (t == 255) bsum[blockIdx.x] = sd[t];
}

__global__ void k_scan_bsums(const int* __restrict__ bsum, int* __restrict__ boff) {
    __shared__ int sd[256];
    int t = threadIdx.x;
    int v = (t < NBLK1) ? bsum[t] : 0;
    sd[t] = v; __syncthreads();
    for (int off = 1; off < 256; off <<= 1) {
        int add = (t >= off) ? sd[t - off] : 0;
        __syncthreads();
        sd[t] += add;
        __syncthreads();
    }
    boff[t] = sd[t] - v;
}

__global__ void k_scan_final(const int* __restrict__ tmp_ex, const int* __restrict__ boff,
                             int* __restrict__ row_start, int* __restrict__ rp) {
    int idx = blockIdx.x * 256 + threadIdx.x;
    if (idx < N_NODES) {
        int v = tmp_ex[idx] + boff[blockIdx.x];
        row_start[idx] = v;
        rp[idx] = v;
    }
    if (idx == 0) row_start[N_NODES] = N_EDGES;
}

// ---------- scatter only the 4B edge id into CSR slots ----------
__global__ void k_perm(const int* __restrict__ dst, int* __restrict__ rp,
                       int* __restrict__ perm_csr) {
    int e = blockIdx.x * 256 + threadIdx.x;
    if (e >= N_EDGES) return;
    int d = dst[e];
    int pos = atomicAdd(&rp[d], 1);
    perm_csr[pos] = e;
}

// ---------- gather-by-slot: ea row (one full line) -> CSR-ordered src + ale ----------
__global__ void k_edge(const int* __restrict__ perm, const int* __restrict__ srcI,
                       const float* __restrict__ ea, const float* __restrict__ Ve,
                       int* __restrict__ src_csr,
                       float4* __restrict__ ale1, float4* __restrict__ ale2) {
    __shared__ float sVe[ED_DIM * 8];
    int t = threadIdx.x;
    if (t < ED_DIM * 8) sVe[t] = Ve[t];
    __syncthreads();
    int i = blockIdx.x * 256 + t;
    if (i >= N_EDGES) return;
    int e = perm[i];
    float a[8];
    #pragma unroll
    for (int k = 0; k < 8; ++k) a[k] = 0.f;
    const float4* er4 = (const float4*)(ea + (long long)e * ED_DIM);
    #pragma unroll
    for (int q = 0; q < ED_DIM / 4; ++q) {
        float4 v = er4[q];
        float ev[4] = {v.x, v.y, v.z, v.w};
        #pragma unroll
        for (int u = 0; u < 4; ++u) {
            #pragma unroll
            for (int k = 0; k < 8; ++k) a[k] += ev[u] * sVe[(q * 4 + u) * 8 + k];
        }
    }
    src_csr[i] = srcI[e];
    ale1[i] = make_float4(a[0], a[1], a[2], a[3]);
    ale2[i] = make_float4(a[4], a[5], a[6], a[7]);
}

// ---------- xw = X @ W  (+ fused per-head al_src / al_dst), 16 nodes/block ----------
template<int K>
__global__ void k_xw(const float* __restrict__ X, const float* __restrict__ W,
                     const float* __restrict__ AS, const float* __restrict__ AD,
                     float* __restrict__ XW, float* __restrict__ ALS, float* __restrict__ ALD) {
    __shared__ float sW[K * HC];
    __shared__ float sX[16 * K];
    int t = threadIdx.x;
    for (int i = t; i < K * HC; i += 256) sW[i] = W[i];
    int nb = blockIdx.x * 16;
    for (int i = t; i < 16 * K; i += 256) sX[i] = X[(long long)nb * K + i];
    __syncthreads();
    int sub = t >> 6, j = t & 63;
    float acc[4] = {0.f, 0.f, 0.f, 0.f};
    #pragma unroll 8
    for (int k = 0; k < K; ++k) {
        float wv = sW[k * HC + j];
        #pragma unroll
        for (int q = 0; q < 4; ++q) acc[q] += sX[(sub + 4 * q) * K + k] * wv;
    }
    float as_ = AS[j], ad_ = AD[j];
    #pragma unroll
    for (int q = 0; q < 4; ++q) {
        int n = nb + sub + 4 * q;
        XW[(long long)n * HC + j] = acc[q];
        float vs = acc[q] * as_, vd = acc[q] * ad_;
        #pragma unroll
        for (int m = 1; m < 16; m <<= 1) { vs += __shfl_xor(vs, m); vd += __shfl_xor(vd, m); }
        if ((j & 15) == 0) {
            int h = j >> 4;
            ALS[n * 4 + h] = vs; ALD[n * 4 + h] = vd;
        }
    }
}

// ---------- wave-per-node softmax aggregation (+self-loop, bias/ReLU[/LN]) ----------
// Plain exp (no max shift): alphas are bounded (|a| <~ 10) by construction.
template<bool DO_LN>
__global__ void k_agg(const int* __restrict__ rs, const int* __restrict__ srcs,
                      const float* __restrict__ ale,
                      const float* __restrict__ ALS, const float* __restrict__ ALD,
                      const float* __restrict__ XW, const float* __restrict__ bias,
                      const float* __restrict__ gam, const float* __restrict__ bet,
                      float* __restrict__ OUT) {
    int n = (blockIdx.x * blockDim.x + threadIdx.x) >> 6;
    if (n >= N_NODES) return;
    int lane = threadIdx.x & 63;
    int h = lane >> 4;
    int e0 = rs[n], e1 = rs[n + 1];
    float adn = ALD[n * 4 + h];
    float acc0 = 0.f, l0 = 0.f, as0 = 0.f;
    float acc1 = 0.f, l1 = 0.f, as1 = 0.f;
    float acc2 = 0.f, l2 = 0.f, as2 = 0.f;
    float acc3 = 0.f, l3 = 0.f, as3 = 0.f;
    int e = e0;
    for (; e + 3 < e1; e += 4) {
        int sA = srcs[e], sB = srcs[e + 1], sC = srcs[e + 2], sD = srcs[e + 3];
        float aeA = ale[(e) * 4 + h];
        float aeB = ale[(e + 1) * 4 + h];
        float aeC = ale[(e + 2) * 4 + h];
        float aeD = ale[(e + 3) * 4 + h];
        float xA = XW[sA * HC + lane];
        float xB = XW[sB * HC + lane];
        float xC = XW[sC * HC + lane];
        float xD = XW[sD * HC + lane];
        float aA = ALS[sA * 4 + h] + adn + aeA;
        float aB = ALS[sB * 4 + h] + adn + aeB;
        float aC = ALS[sC * 4 + h] + adn + aeC;
        float aD = ALS[sD * 4 + h] + adn + aeD;
        aA = aA > 0.f ? aA : NEG_SLOPE * aA;
        aB = aB > 0.f ? aB : NEG_SLOPE * aB;
        aC = aC > 0.f ? aC : NEG_SLOPE * aC;
        aD = aD > 0.f ? aD : NEG_SLOPE * aD;
        float qA = __expf(aA), qB = __expf(aB), qC = __expf(aC), qD = __expf(aD);
        acc0 += qA * xA; l0 += qA; as0 += aeA;
        acc1 += qB * xB; l1 += qB; as1 += aeB;
        acc2 += qC * xC; l2 += qC; as2 += aeC;
        acc3 += qD * xD; l3 += qD; as3 += aeD;
    }
    for (; e < e1; ++e) {
        int sA = srcs[e];
        float aeA = ale[(e) * 4 + h];
        float xA = XW[sA * HC + lane];
        float aA = ALS[sA * 4 + h] + adn + aeA;
        aA = aA > 0.f ? aA : NEG_SLOPE * aA;
        float qA = __expf(aA);
        acc0 += qA * xA; l0 += qA; as0 += aeA;
    }
    // self loop: ale_self = mean of row's ale (linearity of edge projection)
    int d = e1 - e0;
    float invd = 1.f / (float)(d > 0 ? d : 1);
    float aSelf = ALS[n * 4 + h] + adn + (as0 + as1 + as2 + as3) * invd;
    aSelf = aSelf > 0.f ? aSelf : NEG_SLOPE * aSelf;
    float pS = __expf(aSelf);
    float acc = (acc0 + acc1) + (acc2 + acc3) + pS * XW[n * HC + lane];
    float l = (l0 + l1) + (l2 + l3) + pS;
    float v = acc / (l + 1e-16f) + bias[lane];
    v = fmaxf(v, 0.f);
    if (DO_LN) {
        float s1 = v;
        #pragma unroll
        for (int mm = 1; mm < 64; mm <<= 1) s1 += __shfl_xor(s1, mm);
        float mean = s1 * (1.f / 64.f);
        float dd = v - mean;
        float s2 = dd * dd;
        #pragma unroll
        for (int mm = 1; mm < 64; mm <<= 1) s2 += __shfl_xor(s2, mm);
        float var = s2 * (1.f / 64.f);
        v = dd * rsqrtf(var + LN_EPS) * gam[lane] + bet[lane];
    }
    OUT[(long long)n * HC + lane] = v;
}

// ---------- global max pool by (sorted) batch; values >= 0 ----------
__global__ void k_pool(const float* __restrict__ H2, const int* __restrict__ batch,
                       float* __restrict__ pooled) {
    int j = threadIdx.x & 63;
    int r = threadIdx.x >> 6;          // 4 rows in parallel
    int base = blockIdx.x * 128;
    int gcur = -1; float rm = 0.f;
    for (int n = base + r; n < base + 128 && n < N_NODES; n += 4) {
        int g = batch[n];
        if (g != gcur) {
            if (gcur >= 0) atomicMax((unsigned int*)&pooled[gcur * HC + j], __float_as_uint(rm));
            gcur = g; rm = 0.f;
        }
        rm = fmaxf(rm, H2[(long long)n * HC + j]);
    }
    if (gcur >= 0) atomicMax((unsigned int*)&pooled[gcur * HC + j], __float_as_uint(rm));
}

// ---------- head: fc1 + LN + relu + fc2 + log_softmax ----------
__global__ void k_head(const float* __restrict__ pooled,
                       const float* __restrict__ fw1, const float* __restrict__ fb1,
                       const float* __restrict__ g2, const float* __restrict__ be2,
                       const float* __restrict__ fw2, const float* __restrict__ fb2,
                       float* __restrict__ out) {
    int g = blockIdx.x;
    int j = threadIdx.x;                // 64 threads, lanes 0..31 active for math
    float z = 0.f;
    if (j < 32) {
        for (int k = 0; k < HC; ++k) z += pooled[g * HC + k] * fw1[k * 32 + j];
        z += fb1[j];
    }
    float s1 = (j < 32) ? z : 0.f;
    for (int m = 1; m < 32; m <<= 1) s1 += __shfl_xor(s1, m, 32);
    float mean = s1 * (1.f / 32.f);
    float d = z - mean;
    float s2 = (j < 32) ? d * d : 0.f;
    for (int m = 1; m < 32; m <<= 1) s2 += __shfl_xor(s2, m, 32);
    float var = s2 * (1.f / 32.f);
    float zz = 0.f;
    if (j < 32) {
        zz = d * rsqrtf(var + LN_EPS) * g2[j] + be2[j];
        zz = fmaxf(zz, 0.f);
    }
    float p0 = (j < 32) ? zz * fw2[j * NCL + 0] : 0.f;
    float p1 = (j < 32) ? zz * fw2[j * NCL + 1] : 0.f;
    for (int m = 1; m < 32; m <<= 1) { p0 += __shfl_xor(p0, m, 32); p1 += __shfl_xor(p1, m, 32); }
    if (j == 0) {
        float l0 = p0 + fb2[0], l1 = p1 + fb2[1];
        float mx = fmaxf(l0, l1);
        float ls = mx + logf(__expf(l0 - mx) + __expf(l1 - mx));
        out[g * NCL + 0] = l0 - ls;
        out[g * NCL + 1] = l1 - ls;
    }
}

extern "C" void kernel_launch(void* const* d_in, const int* in_sizes, int n_in,
                              void* d_out, int out_size, void* d_ws, size_t ws_size,
                              hipStream_t stream) {
    const float* x   = (const float*)d_in[0];
    const float* ea  = (const float*)d_in[1];
    const float* W1  = (const float*)d_in[2];
    const float* as1 = (const float*)d_in[3];
    const float* ad1 = (const float*)d_in[4];
    const float* We1 = (const float*)d_in[5];
    const float* ae1 = (const float*)d_in[6];
    const float* b1  = (const float*)d_in[7];
    const float* W2  = (const float*)d_in[8];
    const float* as2 = (const float*)d_in[9];
    const float* ad2 = (const float*)d_in[10];
    const float* We2 = (const float*)d_in[11];
    const float* ae2 = (const float*)d_in[12];
    const float* b2  = (const float*)d_in[13];
    const float* g1  = (const float*)d_in[14];
    const float* be1 = (const float*)d_in[15];
    const float* fw1 = (const float*)d_in[16];
    const float* fb1 = (const float*)d_in[17];
    const float* g2  = (const float*)d_in[18];
    const float* be2 = (const float*)d_in[19];
    const float* fw2 = (const float*)d_in[20];
    const float* fb2 = (const float*)d_in[21];
    const int* eidx  = (const int*)d_in[22];
    const int* batch = (const int*)d_in[23];
    const int* srcI = eidx;
    const int* dstI = eidx + N_EDGES;

    char* w = (char*)d_ws;
    auto alloc = [&](size_t bytes) { char* p = w; w += (bytes + 255) & ~(size_t)255; return p; };
    int*   cnt       = (int*)  alloc((size_t)N_NODES * 4);
    int*   row_start = (int*)  alloc((size_t)(N_NODES + 1) * 4);
    int*   rp        = (int*)  alloc((size_t)N_NODES * 4);
    int*   tmp_ex    = (int*)  alloc((size_t)N_NODES * 4);
    int*   bsum      = (int*)  alloc(256 * 4);
    int*   boff      = (int*)  alloc(256 * 4);
    float* Ve        = (float*)alloc(ED_DIM * 8 * 4);
    int*   perm_csr  = (int*)  alloc((size_t)N_EDGES * 4);
    int*   src_csr   = (int*)  alloc((size_t)N_EDGES * 4);
    float4* ale1     = (float4*)alloc((size_t)N_EDGES * 16);
    float4* ale2     = (float4*)alloc((size_t)N_EDGES * 16);
    float* xw1       = (float*)alloc((size_t)N_NODES * HC * 4);   // reused as xw2
    float* als1      = (float*)alloc((size_t)N_NODES * 4 * 4);
    float* ald1      = (float*)alloc((size_t)N_NODES * 4 * 4);
    float* h1        = (float*)alloc((size_t)N_NODES * HC * 4);   // reused as h2
    float* als2      = (float*)alloc((size_t)N_NODES * 4 * 4);
    float* ald2      = (float*)alloc((size_t)N_NODES * 4 * 4);
    float* pooled    = (float*)alloc((size_t)NG * HC * 4);
    float* xw2 = xw1;   // lifetime of xw1 ends at k_agg<true>
    float* h2  = h1;    // lifetime of h1 ends at k_xw<HC>

    hipMemsetAsync(cnt, 0, (size_t)N_NODES * 4, stream);
    hipMemsetAsync(pooled, 0, (size_t)NG * HC * 4, stream);

    k_ve<<<1, 256, 0, stream>>>(We1, ae1, We2, ae2, Ve);
    k_hist<<<N_EDGES / 256, 256, 0, stream>>>(dstI, cnt);
    k_scan_local<<<NBLK1, 256, 0, stream>>>(cnt, tmp_ex, bsum);
    k_scan_bsums<<<1, 256, 0, stream>>>(bsum, boff);
    k_scan_final<<<NBLK1, 256, 0, stream>>>(tmp_ex, boff, row_start, rp);
    k_perm<<<N_EDGES / 256, 256, 0, stream>>>(dstI, rp, perm_csr);
    k_edge<<<N_EDGES / 256, 256, 0, stream>>>(perm_csr, srcI, ea, Ve, src_csr, ale1, ale2);

    // Layer 1: xw + attention logits, aggregate with fused bias/ReLU/LayerNorm
    k_xw<IN_DIM><<<N_NODES / 16, 256, 0, stream>>>(x, W1, as1, ad1, xw1, als1, ald1);
    k_agg<true><<<N_NODES / 4, 256, 0, stream>>>(row_start, src_csr, (const float*)ale1,
                                                 als1, ald1, xw1, b1, g1, be1, h1);
    // Layer 2: fused bias/ReLU only
    k_xw<HC><<<N_NODES / 16, 256, 0, stream>>>(h1, W2, as2, ad2, xw2, als2, ald2);
    k_agg<false><<<N_NODES / 4, 256, 0, stream>>>(row_start, src_csr, (const float*)ale2,
                                                  als2, ald2, xw2, b2, nullptr, nullptr, h2);

    k_pool<<<(N_NODES + 127) / 128, 256, 0, stream>>>(h2, batch, pooled);
    k_head<<<NG, 64, 0, stream>>>(pooled, fw1, fb1, g2, be2, fw2, fb2, (float*)d_out);
}

// Round 7
// 479.149 us; speedup vs baseline: 1.1055x; 1.0444x over previous
//
#include <hip/hip_runtime.h>
#include <math.h>

#define N_NODES 50000
#define N_EDGES 800000
#define IN_DIM 128
#define ED_DIM 32
#define NH 4
#define CH 16
#define HC 64
#define NG 64
#define NCL 2
#define NEG_SLOPE 0.2f
#define LN_EPS 1e-5f
#define NBLK1 196  // ceil(50000/256)

// ---------- fold We @ ae -> Ve[32][8]  (k = layer*4 + head) ----------
__global__ void k_ve(const float* __restrict__ We1, const float* __restrict__ ae1,
                     const float* __restrict__ We2, const float* __restrict__ ae2,
                     float* __restrict__ Ve) {
    int t = threadIdx.x;            // 256 threads
    int d = t >> 3, k = t & 7;
    int l = k >> 2, h = k & 3;
    const float* We = l ? We2 : We1;
    const float* ae = l ? ae2 : ae1;
    float s = 0.f;
    #pragma unroll
    for (int c = 0; c < CH; ++c) s += We[d * HC + h * CH + c] * ae[h * CH + c];
    Ve[d * 8 + k] = s;
}

// ---------- degree histogram ----------
__global__ void k_hist(const int* __restrict__ dst, int* __restrict__ cnt) {
    int e = blockIdx.x * 256 + threadIdx.x;
    if (e < N_EDGES) atomicAdd(&cnt[dst[e]], 1);
}

// ---------- 3-phase exclusive scan of cnt -> row_start (+ rp copy) ----------
__global__ void k_scan_local(const int* __restrict__ cnt, int* __restrict__ tmp_ex,
                             int* __restrict__ bsum) {
    __shared__ int sd[256];
    int t = threadIdx.x, idx = blockIdx.x * 256 + t;
    int v = (idx < N_NODES) ? cnt[idx] : 0;
    sd[t] = v; __syncthreads();
    for (int off = 1; off < 256; off <<= 1) {
        int add = (t >= off) ? sd[t - off] : 0;
        __syncthreads();
        sd[t] += add;
        __syncthreads();
    }
    if (idx < N_NODES) tmp_ex[idx] = sd[t] - v;
    if (t == 255) bsum[blockIdx.x] = sd[t];
}

__global__ void k_scan_bsums(const int* __restrict__ bsum, int* __restrict__ boff) {
    __shared__ int sd[256];
    int t = threadIdx.x;
    int v = (t < NBLK1) ? bsum[t] : 0;
    sd[t] = v; __syncthreads();
    for (int off = 1; off < 256; off <<= 1) {
        int add = (t >= off) ? sd[t - off] : 0;
        __syncthreads();
        sd[t] += add;
        __syncthreads();
    }
    boff[t] = sd[t] - v;
}

__global__ void k_scan_final(const int* __restrict__ tmp_ex, const int* __restrict__ boff,
                             int* __restrict__ row_start, int* __restrict__ rp) {
    int idx = blockIdx.x * 256 + threadIdx.x;
    if (idx < N_NODES) {
        int v = tmp_ex[idx] + boff[blockIdx.x];
        row_start[idx] = v;
        rp[idx] = v;
    }
    if (idx == 0) row_start[N_NODES] = N_EDGES;
}

// ---------- fused: stream ea -> ale8 (edge order) + 4B perm scatter ----------
__global__ void k_edgeperm(const int* __restrict__ dst, const float* __restrict__ ea,
                           const float* __restrict__ Ve, int* __restrict__ rp,
                           int* __restrict__ perm_csr, float* __restrict__ ale8) {
    __shared__ float sVe[ED_DIM * 8];
    int t = threadIdx.x;
    if (t < ED_DIM * 8) sVe[t] = Ve[t];
    __syncthreads();
    int e = blockIdx.x * 256 + t;
    if (e >= N_EDGES) return;
    int d = dst[e];
    float a[8];
    #pragma unroll
    for (int k = 0; k < 8; ++k) a[k] = 0.f;
    const float4* er4 = (const float4*)(ea + (long long)e * ED_DIM);
    #pragma unroll
    for (int q = 0; q < ED_DIM / 4; ++q) {
        float4 v = er4[q];
        float ev[4] = {v.x, v.y, v.z, v.w};
        #pragma unroll
        for (int u = 0; u < 4; ++u) {
            #pragma unroll
            for (int k = 0; k < 8; ++k) a[k] += ev[u] * sVe[(q * 4 + u) * 8 + k];
        }
    }
    int pos = atomicAdd(&rp[d], 1);
    perm_csr[pos] = e;
    float4* ap = (float4*)(ale8 + (long long)e * 8);
    ap[0] = make_float4(a[0], a[1], a[2], a[3]);
    ap[1] = make_float4(a[4], a[5], a[6], a[7]);
}

// ---------- gather (L3-hot) into CSR-ordered streams ----------
__global__ void k_gather(const int* __restrict__ perm, const int* __restrict__ srcI,
                         const float* __restrict__ ale8, int* __restrict__ src_csr,
                         float4* __restrict__ ale1, float4* __restrict__ ale2) {
    int i = blockIdx.x * 256 + threadIdx.x;
    if (i >= N_EDGES) return;
    int e = perm[i];
    const float4* a = (const float4*)(ale8 + (long long)e * 8);
    float4 a0 = a[0];
    float4 a1 = a[1];
    src_csr[i] = srcI[e];
    ale1[i] = a0;
    ale2[i] = a1;
}

// ---------- xw = X @ W  (+ fused per-head al_src / al_dst), 16 nodes/block ----------
template<int K>
__global__ void k_xw(const float* __restrict__ X, const float* __restrict__ W,
                     const float* __restrict__ AS, const float* __restrict__ AD,
                     float* __restrict__ XW, float* __restrict__ ALS, float* __restrict__ ALD) {
    __shared__ float sW[K * HC];
    __shared__ float sX[16 * K];
    int t = threadIdx.x;
    for (int i = t; i < K * HC; i += 256) sW[i] = W[i];
    int nb = blockIdx.x * 16;
    for (int i = t; i < 16 * K; i += 256) sX[i] = X[(long long)nb * K + i];
    __syncthreads();
    int sub = t >> 6, j = t & 63;
    float acc[4] = {0.f, 0.f, 0.f, 0.f};
    #pragma unroll 8
    for (int k = 0; k < K; ++k) {
        float wv = sW[k * HC + j];
        #pragma unroll
        for (int q = 0; q < 4; ++q) acc[q] += sX[(sub + 4 * q) * K + k] * wv;
    }
    float as_ = AS[j], ad_ = AD[j];
    #pragma unroll
    for (int q = 0; q < 4; ++q) {
        int n = nb + sub + 4 * q;
        XW[(long long)n * HC + j] = acc[q];
        float vs = acc[q] * as_, vd = acc[q] * ad_;
        #pragma unroll
        for (int m = 1; m < 16; m <<= 1) { vs += __shfl_xor(vs, m); vd += __shfl_xor(vd, m); }
        if ((j & 15) == 0) {
            int h = j >> 4;
            ALS[n * 4 + h] = vs; ALD[n * 4 + h] = vd;
        }
    }
}

// ---------- wave-per-node softmax aggregation (+self-loop, bias/ReLU[/LN]) ----------
// Plain exp (no max shift): alphas are bounded (|a| <~ 10) by construction.
template<bool DO_LN>
__global__ void k_agg(const int* __restrict__ rs, const int* __restrict__ srcs,
                      const float* __restrict__ ale,
                      const float* __restrict__ ALS, const float* __restrict__ ALD,
                      const float* __restrict__ XW, const float* __restrict__ bias,
                      const float* __restrict__ gam, const float* __restrict__ bet,
                      float* __restrict__ OUT) {
    int n = (blockIdx.x * blockDim.x + threadIdx.x) >> 6;
    if (n >= N_NODES) return;
    int lane = threadIdx.x & 63;
    int h = lane >> 4;
    int e0 = rs[n], e1 = rs[n + 1];
    float adn = ALD[n * 4 + h];
    float acc0 = 0.f, l0 = 0.f, as0 = 0.f;
    float acc1 = 0.f, l1 = 0.f, as1 = 0.f;
    float acc2 = 0.f, l2 = 0.f, as2 = 0.f;
    float acc3 = 0.f, l3 = 0.f, as3 = 0.f;
    int e = e0;
    for (; e + 3 < e1; e += 4) {
        int sA = srcs[e], sB = srcs[e + 1], sC = srcs[e + 2], sD = srcs[e + 3];
        float aeA = ale[(e) * 4 + h];
        float aeB = ale[(e + 1) * 4 + h];
        float aeC = ale[(e + 2) * 4 + h];
        float aeD = ale[(e + 3) * 4 + h];
        float xA = XW[sA * HC + lane];
        float xB = XW[sB * HC + lane];
        float xC = XW[sC * HC + lane];
        float xD = XW[sD * HC + lane];
        float aA = ALS[sA * 4 + h] + adn + aeA;
        float aB = ALS[sB * 4 + h] + adn + aeB;
        float aC = ALS[sC * 4 + h] + adn + aeC;
        float aD = ALS[sD * 4 + h] + adn + aeD;
        aA = aA > 0.f ? aA : NEG_SLOPE * aA;
        aB = aB > 0.f ? aB : NEG_SLOPE * aB;
        aC = aC > 0.f ? aC : NEG_SLOPE * aC;
        aD = aD > 0.f ? aD : NEG_SLOPE * aD;
        float qA = __expf(aA), qB = __expf(aB), qC = __expf(aC), qD = __expf(aD);
        acc0 += qA * xA; l0 += qA; as0 += aeA;
        acc1 += qB * xB; l1 += qB; as1 += aeB;
        acc2 += qC * xC; l2 += qC; as2 += aeC;
        acc3 += qD * xD; l3 += qD; as3 += aeD;
    }
    for (; e < e1; ++e) {
        int sA = srcs[e];
        float aeA = ale[(e) * 4 + h];
        float xA = XW[sA * HC + lane];
        float aA = ALS[sA * 4 + h] + adn + aeA;
        aA = aA > 0.f ? aA : NEG_SLOPE * aA;
        float qA = __expf(aA);
        acc0 += qA * xA; l0 += qA; as0 += aeA;
    }
    // self loop: ale_self = mean of row's ale (linearity of edge projection)
    int d = e1 - e0;
    float invd = 1.f / (float)(d > 0 ? d : 1);
    float aSelf = ALS[n * 4 + h] + adn + (as0 + as1 + as2 + as3) * invd;
    aSelf = aSelf > 0.f ? aSelf : NEG_SLOPE * aSelf;
    float pS = __expf(aSelf);
    float acc = (acc0 + acc1) + (acc2 + acc3) + pS * XW[n * HC + lane];
    float l = (l0 + l1) + (l2 + l3) + pS;
    float v = acc / (l + 1e-16f) + bias[lane];
    v = fmaxf(v, 0.f);
    if (DO_LN) {
        float s1 = v;
        #pragma unroll
        for (int mm = 1; mm < 64; mm <<= 1) s1 += __shfl_xor(s1, mm);
        float mean = s1 * (1.f / 64.f);
        float dd = v - mean;
        float s2 = dd * dd;
        #pragma unroll
        for (int mm = 1; mm < 64; mm <<= 1) s2 += __shfl_xor(s2, mm);
        float var = s2 * (1.f / 64.f);
        v = dd * rsqrtf(var + LN_EPS) * gam[lane] + bet[lane];
    }
    OUT[(long long)n * HC + lane] = v;
}

// ---------- global max pool by (sorted) batch; values >= 0 ----------
__global__ void k_pool(const float* __restrict__ H2, const int* __restrict__ batch,
                       float* __restrict__ pooled) {
    int j = threadIdx.x & 63;
    int r = threadIdx.x >> 6;          // 4 rows in parallel
    int base = blockIdx.x * 128;
    int gcur = -1; float rm = 0.f;
    for (int n = base + r; n < base + 128 && n < N_NODES; n += 4) {
        int g = batch[n];
        if (g != gcur) {
            if (gcur >= 0) atomicMax((unsigned int*)&pooled[gcur * HC + j], __float_as_uint(rm));
            gcur = g; rm = 0.f;
        }
        rm = fmaxf(rm, H2[(long long)n * HC + j]);
    }
    if (gcur >= 0) atomicMax((unsigned int*)&pooled[gcur * HC + j], __float_as_uint(rm));
}

// ---------- head: fc1 + LN + relu + fc2 + log_softmax ----------
__global__ void k_head(const float* __restrict__ pooled,
                       const float* __restrict__ fw1, const float* __restrict__ fb1,
                       const float* __restrict__ g2, const float* __restrict__ be2,
                       const float* __restrict__ fw2, const float* __restrict__ fb2,
                       float* __restrict__ out) {
    int g = blockIdx.x;
    int j = threadIdx.x;                // 64 threads, lanes 0..31 active for math
    float z = 0.f;
    if (j < 32) {
        for (int k = 0; k < HC; ++k) z += pooled[g * HC + k] * fw1[k * 32 + j];
        z += fb1[j];
    }
    float s1 = (j < 32) ? z : 0.f;
    for (int m = 1; m < 32; m <<= 1) s1 += __shfl_xor(s1, m, 32);
    float mean = s1 * (1.f / 32.f);
    float d = z - mean;
    float s2 = (j < 32) ? d * d : 0.f;
    for (int m = 1; m < 32; m <<= 1) s2 += __shfl_xor(s2, m, 32);
    float var = s2 * (1.f / 32.f);
    float zz = 0.f;
    if (j < 32) {
        zz = d * rsqrtf(var + LN_EPS) * g2[j] + be2[j];
        zz = fmaxf(zz, 0.f);
    }
    float p0 = (j < 32) ? zz * fw2[j * NCL + 0] : 0.f;
    float p1 = (j < 32) ? zz * fw2[j * NCL + 1] : 0.f;
    for (int m = 1; m < 32; m <<= 1) { p0 += __shfl_xor(p0, m, 32); p1 += __shfl_xor(p1, m, 32); }
    if (j == 0) {
        float l0 = p0 + fb2[0], l1 = p1 + fb2[1];
        float mx = fmaxf(l0, l1);
        float ls = mx + logf(__expf(l0 - mx) + __expf(l1 - mx));
        out[g * NCL + 0] = l0 - ls;
        out[g * NCL + 1] = l1 - ls;
    }
}

extern "C" void kernel_launch(void* const* d_in, const int* in_sizes, int n_in,
                              void* d_out, int out_size, void* d_ws, size_t ws_size,
                              hipStream_t stream) {
    const float* x   = (const float*)d_in[0];
    const float* ea  = (const float*)d_in[1];
    const float* W1  = (const float*)d_in[2];
    const float* as1 = (const float*)d_in[3];
    const float* ad1 = (const float*)d_in[4];
    const float* We1 = (const float*)d_in[5];
    const float* ae1 = (const float*)d_in[6];
    const float* b1  = (const float*)d_in[7];
    const float* W2  = (const float*)d_in[8];
    const float* as2 = (const float*)d_in[9];
    const float* ad2 = (const float*)d_in[10];
    const float* We2 = (const float*)d_in[11];
    const float* ae2 = (const float*)d_in[12];
    const float* b2  = (const float*)d_in[13];
    const float* g1  = (const float*)d_in[14];
    const float* be1 = (const float*)d_in[15];
    const float* fw1 = (const float*)d_in[16];
    const float* fb1 = (const float*)d_in[17];
    const float* g2  = (const float*)d_in[18];
    const float* be2 = (const float*)d_in[19];
    const float* fw2 = (const float*)d_in[20];
    const float* fb2 = (const float*)d_in[21];
    const int* eidx  = (const int*)d_in[22];
    const int* batch = (const int*)d_in[23];
    const int* srcI = eidx;
    const int* dstI = eidx + N_EDGES;

    char* w = (char*)d_ws;
    auto alloc = [&](size_t bytes) { char* p = w; w += (bytes + 255) & ~(size_t)255; return p; };
    int*   cnt       = (int*)  alloc((size_t)N_NODES * 4);
    int*   row_start = (int*)  alloc((size_t)(N_NODES + 1) * 4);
    int*   rp        = (int*)  alloc((size_t)N_NODES * 4);
    int*   tmp_ex    = (int*)  alloc((size_t)N_NODES * 4);
    int*   bsum      = (int*)  alloc(256 * 4);
    int*   boff      = (int*)  alloc(256 * 4);
    float* Ve        = (float*)alloc(ED_DIM * 8 * 4);
    int*   perm_csr  = (int*)  alloc((size_t)N_EDGES * 4);
    int*   src_csr   = (int*)  alloc((size_t)N_EDGES * 4);
    float* ale8      = (float*)alloc((size_t)N_EDGES * 8 * 4);
    float4* ale1     = (float4*)alloc((size_t)N_EDGES * 16);
    float4* ale2     = (float4*)alloc((size_t)N_EDGES * 16);
    float* xw1       = (float*)alloc((size_t)N_NODES * HC * 4);   // reused as xw2
    float* als1      = (float*)alloc((size_t)N_NODES * 4 * 4);
    float* ald1      = (float*)alloc((size_t)N_NODES * 4 * 4);
    float* h1        = (float*)alloc((size_t)N_NODES * HC * 4);   // reused as h2
    float* als2      = (float*)alloc((size_t)N_NODES * 4 * 4);
    float* ald2      = (float*)alloc((size_t)N_NODES * 4 * 4);
    float* pooled    = (float*)alloc((size_t)NG * HC * 4);
    float* xw2 = xw1;   // lifetime of xw1 ends at k_agg<true>
    float* h2  = h1;    // lifetime of h1 ends at k_xw<HC>

    hipMemsetAsync(cnt, 0, (size_t)N_NODES * 4, stream);
    hipMemsetAsync(pooled, 0, (size_t)NG * HC * 4, stream);

    k_ve<<<1, 256, 0, stream>>>(We1, ae1, We2, ae2, Ve);
    k_hist<<<N_EDGES / 256, 256, 0, stream>>>(dstI, cnt);
    k_scan_local<<<NBLK1, 256, 0, stream>>>(cnt, tmp_ex, bsum);
    k_scan_bsums<<<1, 256, 0, stream>>>(bsum, boff);
    k_scan_final<<<NBLK1, 256, 0, stream>>>(tmp_ex, boff, row_start, rp);
    k_edgeperm<<<N_EDGES / 256, 256, 0, stream>>>(dstI, ea, Ve, rp, perm_csr, ale8);
    k_gather<<<N_EDGES / 256, 256, 0, stream>>>(perm_csr, srcI, ale8, src_csr, ale1, ale2);

    // Layer 1: xw + attention logits, aggregate with fused bias/ReLU/LayerNorm
    k_xw<IN_DIM><<<N_NODES / 16, 256, 0, stream>>>(x, W1, as1, ad1, xw1, als1, ald1);
    k_agg<true><<<N_NODES / 4, 256, 0, stream>>>(row_start, src_csr, (const float*)ale1,
                                                 als1, ald1, xw1, b1, g1, be1, h1);
    // Layer 2: fused bias/ReLU only
    k_xw<HC><<<N_NODES / 16, 256, 0, stream>>>(h1, W2, as2, ad2, xw2, als2, ald2);
    k_agg<false><<<N_NODES / 4, 256, 0, stream>>>(row_start, src_csr, (const float*)ale2,
                                                  als2, ald2, xw2, b2, nullptr, nullptr, h2);

    k_pool<<<(N_NODES + 127) / 128, 256, 0, stream>>>(h2, batch, pooled);
    k_head<<<NG, 64, 0, stream>>>(pooled, fw1, fb1, g2, be2, fw2, fb2, (float*)d_out);
}

// Round 8
// 470.411 us; speedup vs baseline: 1.1261x; 1.0186x over previous
//
#include <hip/hip_runtime.h>
#include <math.h>

#define N_NODES 50000
#define N_EDGES 800000
#define IN_DIM 128
#define ED_DIM 32
#define NH 4
#define CH 16
#define HC 64
#define NG 64
#define NCL 2
#define NEG_SLOPE 0.2f
#define LN_EPS 1e-5f
#define NBLK1 196  // ceil(50000/256)

// ---------- fold We @ ae -> Ve[32][8]  (k = layer*4 + head) ----------
__global__ void k_ve(const float* __restrict__ We1, const float* __restrict__ ae1,
                     const float* __restrict__ We2, const float* __restrict__ ae2,
                     float* __restrict__ Ve) {
    int t = threadIdx.x;            // 256 threads
    int d = t >> 3, k = t & 7;
    int l = k >> 2, h = k & 3;
    const float* We = l ? We2 : We1;
    const float* ae = l ? ae2 : ae1;
    float s = 0.f;
    #pragma unroll
    for (int c = 0; c < CH; ++c) s += We[d * HC + h * CH + c] * ae[h * CH + c];
    Ve[d * 8 + k] = s;
}

// ---------- degree histogram; atomic return = rank of edge within its row ----------
__global__ void k_hist(const int* __restrict__ dst, int* __restrict__ cnt,
                       int* __restrict__ rank_e) {
    int e = blockIdx.x * 256 + threadIdx.x;
    if (e < N_EDGES) rank_e[e] = atomicAdd(&cnt[dst[e]], 1);
}

// ---------- 3-phase exclusive scan of cnt -> row_start ----------
__global__ void k_scan_local(const int* __restrict__ cnt, int* __restrict__ tmp_ex,
                             int* __restrict__ bsum) {
    __shared__ int sd[256];
    int t = threadIdx.x, idx = blockIdx.x * 256 + t;
    int v = (idx < N_NODES) ? cnt[idx] : 0;
    sd[t] = v; __syncthreads();
    for (int off = 1; off < 256; off <<= 1) {
        int add = (t >= off) ? sd[t - off] : 0;
        __syncthreads();
        sd[t] += add;
        __syncthreads();
    }
    if (idx < N_NODES) tmp_ex[idx] = sd[t] - v;
    if (t == 255) bsum[blockIdx.x] = sd[t];
}

__global__ void k_scan_bsums(const int* __restrict__ bsum, int* __restrict__ boff) {
    __shared__ int sd[256];
    int t = threadIdx.x;
    int v = (t < NBLK1) ? bsum[t] : 0;
    sd[t] = v; __syncthreads();
    for (int off = 1; off < 256; off <<= 1) {
        int add = (t >= off) ? sd[t - off] : 0;
        __syncthreads();
        sd[t] += add;
        __syncthreads();
    }
    boff[t] = sd[t] - v;
}

__global__ void k_scan_final(const int* __restrict__ tmp_ex, const int* __restrict__ boff,
                             int* __restrict__ row_start) {
    int idx = blockIdx.x * 256 + threadIdx.x;
    if (idx < N_NODES) row_start[idx] = tmp_ex[idx] + boff[blockIdx.x];
    if (idx == 0) row_start[N_NODES] = N_EDGES;
}

// ---------- scatter edge id to precomputed slot (no atomics) ----------
__global__ void k_perm(const int* __restrict__ dst, const int* __restrict__ rank_e,
                       const int* __restrict__ row_start, int* __restrict__ perm_csr) {
    int e = blockIdx.x * 256 + threadIdx.x;
    if (e >= N_EDGES) return;
    int pos = row_start[dst[e]] + rank_e[e];
    perm_csr[pos] = e;
}

// ---------- pure streaming: ea -> ale8 (edge order) ----------
__global__ void k_edge(const float* __restrict__ ea, const float* __restrict__ Ve,
                       float* __restrict__ ale8) {
    __shared__ float sVe[ED_DIM * 8];
    int t = threadIdx.x;
    if (t < ED_DIM * 8) sVe[t] = Ve[t];
    __syncthreads();
    int e = blockIdx.x * 256 + t;
    if (e >= N_EDGES) return;
    float a[8];
    #pragma unroll
    for (int k = 0; k < 8; ++k) a[k] = 0.f;
    const float4* er4 = (const float4*)(ea + (long long)e * ED_DIM);
    #pragma unroll
    for (int q = 0; q < ED_DIM / 4; ++q) {
        float4 v = er4[q];
        float ev[4] = {v.x, v.y, v.z, v.w};
        #pragma unroll
        for (int u = 0; u < 4; ++u) {
            #pragma unroll
            for (int k = 0; k < 8; ++k) a[k] += ev[u] * sVe[(q * 4 + u) * 8 + k];
        }
    }
    float4* ap = (float4*)(ale8 + (long long)e * 8);
    ap[0] = make_float4(a[0], a[1], a[2], a[3]);
    ap[1] = make_float4(a[4], a[5], a[6], a[7]);
}

// ---------- gather (L3-hot) into CSR-ordered streams ----------
__global__ void k_gather(const int* __restrict__ perm, const int* __restrict__ srcI,
                         const float* __restrict__ ale8, int* __restrict__ src_csr,
                         float4* __restrict__ ale1, float4* __restrict__ ale2) {
    int i = blockIdx.x * 256 + threadIdx.x;
    if (i >= N_EDGES) return;
    int e = perm[i];
    const float4* a = (const float4*)(ale8 + (long long)e * 8);
    float4 a0 = a[0];
    float4 a1 = a[1];
    src_csr[i] = srcI[e];
    ale1[i] = a0;
    ale2[i] = a1;
}

// ---------- xw = X @ W  (+ fused per-head al_src / al_dst), 16 nodes/block ----------
template<int K>
__global__ void k_xw(const float* __restrict__ X, const float* __restrict__ W,
                     const float* __restrict__ AS, const float* __restrict__ AD,
                     float* __restrict__ XW, float* __restrict__ ALS, float* __restrict__ ALD) {
    __shared__ float sW[K * HC];
    __shared__ float sX[16 * K];
    int t = threadIdx.x;
    for (int i = t; i < K * HC; i += 256) sW[i] = W[i];
    int nb = blockIdx.x * 16;
    for (int i = t; i < 16 * K; i += 256) sX[i] = X[(long long)nb * K + i];
    __syncthreads();
    int sub = t >> 6, j = t & 63;
    float acc[4] = {0.f, 0.f, 0.f, 0.f};
    #pragma unroll 8
    for (int k = 0; k < K; ++k) {
        float wv = sW[k * HC + j];
        #pragma unroll
        for (int q = 0; q < 4; ++q) acc[q] += sX[(sub + 4 * q) * K + k] * wv;
    }
    float as_ = AS[j], ad_ = AD[j];
    #pragma unroll
    for (int q = 0; q < 4; ++q) {
        int n = nb + sub + 4 * q;
        XW[(long long)n * HC + j] = acc[q];
        float vs = acc[q] * as_, vd = acc[q] * ad_;
        #pragma unroll
        for (int m = 1; m < 16; m <<= 1) { vs += __shfl_xor(vs, m); vd += __shfl_xor(vd, m); }
        if ((j & 15) == 0) {
            int h = j >> 4;
            ALS[n * 4 + h] = vs; ALD[n * 4 + h] = vd;
        }
    }
}

// ---------- wave-per-node softmax aggregation (+self-loop, bias/ReLU[/LN]) ----------
// Plain exp (no max shift): alphas are bounded (|a| <~ 10) by construction.
template<bool DO_LN>
__global__ void k_agg(const int* __restrict__ rs, const int* __restrict__ srcs,
                      const float* __restrict__ ale,
                      const float* __restrict__ ALS, const float* __restrict__ ALD,
                      const float* __restrict__ XW, const float* __restrict__ bias,
                      const float* __restrict__ gam, const float* __restrict__ bet,
                      float* __restrict__ OUT) {
    int n = (blockIdx.x * blockDim.x + threadIdx.x) >> 6;
    if (n >= N_NODES) return;
    int lane = threadIdx.x & 63;
    int h = lane >> 4;
    int e0 = rs[n], e1 = rs[n + 1];
    float adn = ALD[n * 4 + h];
    float acc0 = 0.f, l0 = 0.f, as0 = 0.f;
    float acc1 = 0.f, l1 = 0.f, as1 = 0.f;
    float acc2 = 0.f, l2 = 0.f, as2 = 0.f;
    float acc3 = 0.f, l3 = 0.f, as3 = 0.f;
    int e = e0;
    for (; e + 3 < e1; e += 4) {
        int sA = srcs[e], sB = srcs[e + 1], sC = srcs[e + 2], sD = srcs[e + 3];
        float aeA = ale[(e) * 4 + h];
        float aeB = ale[(e + 1) * 4 + h];
        float aeC = ale[(e + 2) * 4 + h];
        float aeD = ale[(e + 3) * 4 + h];
        float xA = XW[sA * HC + lane];
        float xB = XW[sB * HC + lane];
        float xC = XW[sC * HC + lane];
        float xD = XW[sD * HC + lane];
        float aA = ALS[sA * 4 + h] + adn + aeA;
        float aB = ALS[sB * 4 + h] + adn + aeB;
        float aC = ALS[sC * 4 + h] + adn + aeC;
        float aD = ALS[sD * 4 + h] + adn + aeD;
        aA = aA > 0.f ? aA : NEG_SLOPE * aA;
        aB = aB > 0.f ? aB : NEG_SLOPE * aB;
        aC = aC > 0.f ? aC : NEG_SLOPE * aC;
        aD = aD > 0.f ? aD : NEG_SLOPE * aD;
        float qA = __expf(aA), qB = __expf(aB), qC = __expf(aC), qD = __expf(aD);
        acc0 += qA * xA; l0 += qA; as0 += aeA;
        acc1 += qB * xB; l1 += qB; as1 += aeB;
        acc2 += qC * xC; l2 += qC; as2 += aeC;
        acc3 += qD * xD; l3 += qD; as3 += aeD;
    }
    for (; e < e1; ++e) {
        int sA = srcs[e];
        float aeA = ale[(e) * 4 + h];
        float xA = XW[sA * HC + lane];
        float aA = ALS[sA * 4 + h] + adn + aeA;
        aA = aA > 0.f ? aA : NEG_SLOPE * aA;
        float qA = __expf(aA);
        acc0 += qA * xA; l0 += qA; as0 += aeA;
    }
    // self loop: ale_self = mean of row's ale (linearity of edge projection)
    int d = e1 - e0;
    float invd = 1.f / (float)(d > 0 ? d : 1);
    float aSelf = ALS[n * 4 + h] + adn + (as0 + as1 + as2 + as3) * invd;
    aSelf = aSelf > 0.f ? aSelf : NEG_SLOPE * aSelf;
    float pS = __expf(aSelf);
    float acc = (acc0 + acc1) + (acc2 + acc3) + pS * XW[n * HC + lane];
    float l = (l0 + l1) + (l2 + l3) + pS;
    float v = acc / (l + 1e-16f) + bias[lane];
    v = fmaxf(v, 0.f);
    if (DO_LN) {
        float s1 = v;
        #pragma unroll
        for (int mm = 1; mm < 64; mm <<= 1) s1 += __shfl_xor(s1, mm);
        float mean = s1 * (1.f / 64.f);
        float dd = v - mean;
        float s2 = dd * dd;
        #pragma unroll
        for (int mm = 1; mm < 64; mm <<= 1) s2 += __shfl_xor(s2, mm);
        float var = s2 * (1.f / 64.f);
        v = dd * rsqrtf(var + LN_EPS) * gam[lane] + bet[lane];
    }
    OUT[(long long)n * HC + lane] = v;
}

// ---------- global max pool by (sorted) batch; values >= 0 ----------
__global__ void k_pool(const float* __restrict__ H2, const int* __restrict__ batch,
                       float* __restrict__ pooled) {
    int j = threadIdx.x & 63;
    int r = threadIdx.x >> 6;          // 4 rows in parallel
    int base = blockIdx.x * 128;
    int gcur = -1; float rm = 0.f;
    for (int n = base + r; n < base + 128 && n < N_NODES; n += 4) {
        int g = batch[n];
        if (g != gcur) {
            if (gcur >= 0) atomicMax((unsigned int*)&pooled[gcur * HC + j], __float_as_uint(rm));
            gcur = g; rm = 0.f;
        }
        rm = fmaxf(rm, H2[(long long)n * HC + j]);
    }
    if (gcur >= 0) atomicMax((unsigned int*)&pooled[gcur * HC + j], __float_as_uint(rm));
}

// ---------- head: fc1 + LN + relu + fc2 + log_softmax ----------
__global__ void k_head(const float* __restrict__ pooled,
                       const float* __restrict__ fw1, const float* __restrict__ fb1,
                       const float* __restrict__ g2, const float* __restrict__ be2,
                       const float* __restrict__ fw2, const float* __restrict__ fb2,
                       float* __restrict__ out) {
    int g = blockIdx.x;
    int j = threadIdx.x;                // 64 threads, lanes 0..31 active for math
    float z = 0.f;
    if (j < 32) {
        for (int k = 0; k < HC; ++k) z += pooled[g * HC + k] * fw1[k * 32 + j];
        z += fb1[j];
    }
    float s1 = (j < 32) ? z : 0.f;
    for (int m = 1; m < 32; m <<= 1) s1 += __shfl_xor(s1, m, 32);
    float mean = s1 * (1.f / 32.f);
    float d = z - mean;
    float s2 = (j < 32) ? d * d : 0.f;
    for (int m = 1; m < 32; m <<= 1) s2 += __shfl_xor(s2, m, 32);
    float var = s2 * (1.f / 32.f);
    float zz = 0.f;
    if (j < 32) {
        zz = d * rsqrtf(var + LN_EPS) * g2[j] + be2[j];
        zz = fmaxf(zz, 0.f);
    }
    float p0 = (j < 32) ? zz * fw2[j * NCL + 0] : 0.f;
    float p1 = (j < 32) ? zz * fw2[j * NCL + 1] : 0.f;
    for (int m = 1; m < 32; m <<= 1) { p0 += __shfl_xor(p0, m, 32); p1 += __shfl_xor(p1, m, 32); }
    if (j == 0) {
        float l0 = p0 + fb2[0], l1 = p1 + fb2[1];
        float mx = fmaxf(l0, l1);
        float ls = mx + logf(__expf(l0 - mx) + __expf(l1 - mx));
        out[g * NCL + 0] = l0 - ls;
        out[g * NCL + 1] = l1 - ls;
    }
}

extern "C" void kernel_launch(void* const* d_in, const int* in_sizes, int n_in,
                              void* d_out, int out_size, void* d_ws, size_t ws_size,
                              hipStream_t stream) {
    const float* x   = (const float*)d_in[0];
    const float* ea  = (const float*)d_in[1];
    const float* W1  = (const float*)d_in[2];
    const float* as1 = (const float*)d_in[3];
    const float* ad1 = (const float*)d_in[4];
    const float* We1 = (const float*)d_in[5];
    const float* ae1 = (const float*)d_in[6];
    const float* b1  = (const float*)d_in[7];
    const float* W2  = (const float*)d_in[8];
    const float* as2 = (const float*)d_in[9];
    const float* ad2 = (const float*)d_in[10];
    const float* We2 = (const float*)d_in[11];
    const float* ae2 = (const float*)d_in[12];
    const float* b2  = (const float*)d_in[13];
    const float* g1  = (const float*)d_in[14];
    const float* be1 = (const float*)d_in[15];
    const float* fw1 = (const float*)d_in[16];
    const float* fb1 = (const float*)d_in[17];
    const float* g2  = (const float*)d_in[18];
    const float* be2 = (const float*)d_in[19];
    const float* fw2 = (const float*)d_in[20];
    const float* fb2 = (const float*)d_in[21];
    const int* eidx  = (const int*)d_in[22];
    const int* batch = (const int*)d_in[23];
    const int* srcI = eidx;
    const int* dstI = eidx + N_EDGES;

    char* w = (char*)d_ws;
    auto alloc = [&](size_t bytes) { char* p = w; w += (bytes + 255) & ~(size_t)255; return p; };
    int*   cnt       = (int*)  alloc((size_t)N_NODES * 4);
    int*   row_start = (int*)  alloc((size_t)(N_NODES + 1) * 4);
    int*   rank_e    = (int*)  alloc((size_t)N_EDGES * 4);
    int*   tmp_ex    = (int*)  alloc((size_t)N_NODES * 4);
    int*   bsum      = (int*)  alloc(256 * 4);
    int*   boff      = (int*)  alloc(256 * 4);
    float* Ve        = (float*)alloc(ED_DIM * 8 * 4);
    int*   perm_csr  = (int*)  alloc((size_t)N_EDGES * 4);
    int*   src_csr   = (int*)  alloc((size_t)N_EDGES * 4);
    float* ale8      = (float*)alloc((size_t)N_EDGES * 8 * 4);
    float4* ale1     = (float4*)alloc((size_t)N_EDGES * 16);
    float4* ale2     = (float4*)alloc((size_t)N_EDGES * 16);
    float* xw1       = (float*)alloc((size_t)N_NODES * HC * 4);   // reused as xw2
    float* als1      = (float*)alloc((size_t)N_NODES * 4 * 4);
    float* ald1      = (float*)alloc((size_t)N_NODES * 4 * 4);
    float* h1        = (float*)alloc((size_t)N_NODES * HC * 4);   // reused as h2
    float* als2      = (float*)alloc((size_t)N_NODES * 4 * 4);
    float* ald2      = (float*)alloc((size_t)N_NODES * 4 * 4);
    float* pooled    = (float*)alloc((size_t)NG * HC * 4);
    float* xw2 = xw1;   // lifetime of xw1 ends at k_agg<true>
    float* h2  = h1;    // lifetime of h1 ends at k_xw<HC>

    hipMemsetAsync(cnt, 0, (size_t)N_NODES * 4, stream);
    hipMemsetAsync(pooled, 0, (size_t)NG * HC * 4, stream);

    k_ve<<<1, 256, 0, stream>>>(We1, ae1, We2, ae2, Ve);
    k_hist<<<N_EDGES / 256, 256, 0, stream>>>(dstI, cnt, rank_e);
    k_scan_local<<<NBLK1, 256, 0, stream>>>(cnt, tmp_ex, bsum);
    k_scan_bsums<<<1, 256, 0, stream>>>(bsum, boff);
    k_scan_final<<<NBLK1, 256, 0, stream>>>(tmp_ex, boff, row_start);
    k_edge<<<N_EDGES / 256, 256, 0, stream>>>(ea, Ve, ale8);
    k_perm<<<N_EDGES / 256, 256, 0, stream>>>(dstI, rank_e, row_start, perm_csr);
    k_gather<<<N_EDGES / 256, 256, 0, stream>>>(perm_csr, srcI, ale8, src_csr, ale1, ale2);

    // Layer 1: xw + attention logits, aggregate with fused bias/ReLU/LayerNorm
    k_xw<IN_DIM><<<N_NODES / 16, 256, 0, stream>>>(x, W1, as1, ad1, xw1, als1, ald1);
    k_agg<true><<<N_NODES / 4, 256, 0, stream>>>(row_start, src_csr, (const float*)ale1,
                                                 als1, ald1, xw1, b1, g1, be1, h1);
    // Layer 2: fused bias/ReLU only
    k_xw<HC><<<N_NODES / 16, 256, 0, stream>>>(h1, W2, as2, ad2, xw2, als2, ald2);
    k_agg<false><<<N_NODES / 4, 256, 0, stream>>>(row_start, src_csr, (const float*)ale2,
                                                  als2, ald2, xw2, b2, nullptr, nullptr, h2);

    k_pool<<<(N_NODES + 127) / 128, 256, 0, stream>>>(h2, batch, pooled);
    k_head<<<NG, 64, 0, stream>>>(pooled, fw1, fb1, g2, be2, fw2, fb2, (float*)d_out);
}